// Round 7
// baseline (319.330 us; speedup 1.0000x reference)
//
#include <hip/hip_runtime.h>
#include <hip/hip_bf16.h>
#include <math.h>

typedef __attribute__((ext_vector_type(8))) short short8;
typedef __attribute__((ext_vector_type(4))) float f32x4;
typedef unsigned short u16;

#define Sn 1024
#define En 256
#define Hn 512
#define Ln 16

__device__ inline u16 bf16b(float x) {
    union { __hip_bfloat16 h; u16 u; } cvt;
    cvt.h = __float2bfloat16(x);
    return cvt.u;
}

__device__ inline float b2f(u16 u) {
    union { unsigned int i; float f; } cvt;
    cvt.i = ((unsigned int)u) << 16;
    return cvt.f;
}

// ---------------- K0: fused weight-pack + embed/GELU
__global__ void prep_embed(const float* __restrict__ wA, const float* __restrict__ wB,
                           const float* __restrict__ wS, u16* __restrict__ Wt,
                           const int* __restrict__ sent, const int* __restrict__ mask,
                           const float* __restrict__ ce_w, const float* __restrict__ me_w,
                           u16* __restrict__ vemb) {
    int bx = blockIdx.x;
    if (bx < 1088) {
        int idx = bx * 256 + threadIdx.x;
        int n = idx >> 8;
        int k = idx & 255;
        float v = 0.f;
        if (n < 512)       v = wA[k * 512 + n];
        else if (n < 1024) v = wB[k * 512 + (n - 512)];
        else if (n < 1040) v = wS[k * 16 + (n - 1024)];
        Wt[idx] = bf16b(v);
    } else {
        int row = bx - 1088;
        int e = threadIdx.x;
        int s = sent[row];
        int m = mask[row];
        float ce = ce_w[s * En + e];
        float me = me_w[m * En + e];
        float g = 0.5f * me * (1.f + erff(me * 0.70710678118654752f));
        vemb[row * En + e] = bf16b(ce * g);
    }
}

// ---------------- K1: GEMM1  C(4096 x 1040) = vemb(4096x256) @ W(256x1040)
#define LDP 136   // 128 + 8 pad (shorts)
__global__ __launch_bounds__(256, 2) void gemm1(const u16* __restrict__ A, const u16* __restrict__ Bt,
                                                const float* __restrict__ bA, const float* __restrict__ bB,
                                                const float* __restrict__ bS,
                                                u16* __restrict__ va, u16* __restrict__ vb,
                                                float* __restrict__ vd,
                                                float* __restrict__ dmn, float* __restrict__ dmx) {
    __shared__ __align__(16) u16 As[64 * LDP];
    __shared__ __align__(16) u16 Bs[64 * LDP];
    int tid = threadIdx.x;
    int m0 = blockIdx.x * 64, n0 = blockIdx.y * 64;
    int lane = tid & 63, w = tid >> 6;
    int lrow = lane & 15, quad = lane >> 4;

    f32x4 acc[4];
    for (int nt = 0; nt < 4; nt++) acc[nt] = (f32x4){0.f, 0.f, 0.f, 0.f};

    for (int kb = 0; kb < 2; kb++) {            // K = 256 = 2 * 128
        for (int i = 0; i < 4; i++) {
            int off = (i * 256 + tid) * 8;
            int r = off >> 7, c = off & 127;
            *(short8*)&As[r * LDP + c] = *(const short8*)&A[(m0 + r) * 256 + kb * 128 + c];
            *(short8*)&Bs[r * LDP + c] = *(const short8*)&Bt[(n0 + r) * 256 + kb * 128 + c];
        }
        __syncthreads();
        for (int ks = 0; ks < 4; ks++) {
            short8 a = *(const short8*)&As[(w * 16 + lrow) * LDP + ks * 32 + quad * 8];
            for (int nt = 0; nt < 4; nt++) {
                short8 b = *(const short8*)&Bs[(nt * 16 + lrow) * LDP + ks * 32 + quad * 8];
                acc[nt] = __builtin_amdgcn_mfma_f32_16x16x32_bf16(a, b, acc[nt], 0, 0, 0);
            }
        }
        __syncthreads();
    }
    int mbase = m0 + w * 16 + quad * 4;
    if (blockIdx.y < 8) {
        for (int nt = 0; nt < 4; nt++) {
            int n = n0 + nt * 16 + lrow;
            float bias = bA[n];
            for (int r = 0; r < 4; r++)
                va[(mbase + r) * 512 + n] = bf16b(acc[nt][r] + bias);
        }
    } else if (blockIdx.y < 16) {
        for (int nt = 0; nt < 4; nt++) {
            int n = n0 + nt * 16 + lrow - 512;
            float bias = bB[n];
            for (int r = 0; r < 4; r++) {
                float x = acc[nt][r] + bias;
                vb[(mbase + r) * 512 + n] = bf16b(1.f / (1.f + __expf(-x)));
            }
        }
    } else {
        float bias = bS[lrow];
        for (int r = 0; r < 4; r++) {
            float x = acc[0][r] + bias;
            x = x > 0.f ? x : 0.f;
            vd[(mbase + r) * 16 + lrow] = x;
            float mn = x, mx = x;
            for (int d = 1; d < 16; d <<= 1) {
                mn = fminf(mn, __shfl_xor(mn, d));
                mx = fmaxf(mx, __shfl_xor(mx, d));
            }
            if (lrow == 0) {
                dmn[mbase + r] = mn;
                dmx[mbase + r] = mx;
            }
        }
    }
}

// ---------------- K2: batched GEMM2, 128x128 tile: vc[b] = va[b] @ vb[b]^T / H -> bf16
#define LDB 72   // 64 + 8 pad (shorts)
__global__ __launch_bounds__(256, 2) void gemm2(const u16* __restrict__ va_g, const u16* __restrict__ vb_g,
                                                u16* __restrict__ vc) {
    __shared__ __align__(16) u16 As[128 * LDB];
    __shared__ __align__(16) u16 Bs[128 * LDB];
    int tid = threadIdx.x;
    int b = blockIdx.z;
    int m0 = blockIdx.x * 128, n0 = blockIdx.y * 128;
    const u16* A  = va_g + (size_t)b * 1024 * 512;
    const u16* Bt = vb_g + (size_t)b * 1024 * 512;
    int lane = tid & 63, w = tid >> 6;
    int wr = (w & 1) * 64, wc = (w >> 1) * 64;
    int lrow = lane & 15, quad = lane >> 4;

    f32x4 acc[4][4];
    for (int mt = 0; mt < 4; mt++)
        for (int nt = 0; nt < 4; nt++)
            acc[mt][nt] = (f32x4){0.f, 0.f, 0.f, 0.f};

    for (int kb = 0; kb < 8; kb++) {            // K = 512 = 8 * 64
        for (int i = 0; i < 4; i++) {           // stage 128x64 each (1024 short8 / 256 thr)
            int v = i * 256 + tid;
            int r = v >> 3, c8 = (v & 7) * 8;
            *(short8*)&As[r * LDB + c8] = *(const short8*)&A[(m0 + r) * 512 + kb * 64 + c8];
            *(short8*)&Bs[r * LDB + c8] = *(const short8*)&Bt[(n0 + r) * 512 + kb * 64 + c8];
        }
        __syncthreads();
        for (int ks = 0; ks < 2; ks++) {
            short8 af[4], bf[4];
            for (int mt = 0; mt < 4; mt++)
                af[mt] = *(const short8*)&As[(wr + mt * 16 + lrow) * LDB + ks * 32 + quad * 8];
            for (int nt = 0; nt < 4; nt++)
                bf[nt] = *(const short8*)&Bs[(wc + nt * 16 + lrow) * LDB + ks * 32 + quad * 8];
            for (int mt = 0; mt < 4; mt++)
                for (int nt = 0; nt < 4; nt++)
                    acc[mt][nt] = __builtin_amdgcn_mfma_f32_16x16x32_bf16(af[mt], bf[nt], acc[mt][nt], 0, 0, 0);
        }
        __syncthreads();
    }
    const float invH = 1.0f / 512.0f;
    u16* C = vc + (size_t)b * 1024 * 1024;
    for (int mt = 0; mt < 4; mt++) {
        int mm = m0 + wr + mt * 16 + quad * 4;
        for (int nt = 0; nt < 4; nt++) {
            int n = n0 + wc + nt * 16 + lrow;
            for (int r = 0; r < 4; r++)
                C[(size_t)(mm + r) * 1024 + n] = bf16b(acc[mt][nt][r] * invH);
        }
    }
}

// ---------------- K3: pred = softmax(vc[b,i,j] * vd[b,j,:]) over L=16; 4 lanes per group
__global__ __launch_bounds__(256) void expand(const u16* __restrict__ vc, const float* __restrict__ vd,
                                              const float* __restrict__ dmn, const float* __restrict__ dmx,
                                              float* __restrict__ out) {
    int gid = blockIdx.x * 256 + threadIdx.x;   // 16,777,216 threads
    int t = gid & 3;
    int grp = gid >> 2;                          // (b*S+i)*S + j
    int j = grp & 1023;
    int bi = grp >> 10;
    int b = bi >> 10;
    float c = b2f(__builtin_nontemporal_load(&vc[grp]));
    int rowd = b * 1024 + j;
    f32x4 d = *(const f32x4*)&vd[rowd * 16 + t * 4];
    float m = (c >= 0.f) ? c * dmx[rowd] : c * dmn[rowd];
    float e0 = __expf(c * d.x - m);
    float e1 = __expf(c * d.y - m);
    float e2 = __expf(c * d.z - m);
    float e3 = __expf(c * d.w - m);
    float s = e0 + e1 + e2 + e3;
    s += __shfl_xor(s, 1);
    s += __shfl_xor(s, 2);
    float inv = 1.f / s;
    f32x4 o;
    o.x = e0 * inv; o.y = e1 * inv; o.z = e2 * inv; o.w = e3 * inv;
    __builtin_nontemporal_store(o, (f32x4*)&out[(size_t)grp * 16 + t * 4]);
}

extern "C" void kernel_launch(void* const* d_in, const int* in_sizes, int n_in,
                              void* d_out, int out_size, void* d_ws, size_t ws_size,
                              hipStream_t stream) {
    const int*   sent = (const int*)d_in[0];
    const int*   mask = (const int*)d_in[1];
    const float* ce_w = (const float*)d_in[2];
    const float* me_w = (const float*)d_in[3];
    const float* wA   = (const float*)d_in[4];
    const float* bA   = (const float*)d_in[5];
    const float* wB   = (const float*)d_in[6];
    const float* bB   = (const float*)d_in[7];
    const float* wS   = (const float*)d_in[8];
    const float* bS   = (const float*)d_in[9];
    float* out = (float*)d_out;

    char* ws = (char*)d_ws;
    u16* vemb = (u16*)ws;  ws += (size_t)4096 * 256 * 2;
    u16* Wt   = (u16*)ws;  ws += (size_t)1088 * 256 * 2;
    u16* va   = (u16*)ws;  ws += (size_t)4096 * 512 * 2;
    u16* vb   = (u16*)ws;  ws += (size_t)4096 * 512 * 2;
    float* vd  = (float*)ws;  ws += (size_t)4096 * 16 * 4;
    float* dmn = (float*)ws;  ws += (size_t)4096 * 4;
    float* dmx = (float*)ws;  ws += (size_t)4096 * 4;
    u16* vc   = (u16*)ws;  ws += (size_t)4 * 1024 * 1024 * 2;

    prep_embed<<<5184, 256, 0, stream>>>(wA, wB, wS, Wt, sent, mask, ce_w, me_w, vemb);
    gemm1<<<dim3(64, 17), 256, 0, stream>>>(vemb, Wt, bA, bB, bS, va, vb, vd, dmn, dmx);
    gemm2<<<dim3(8, 8, 4), 256, 0, stream>>>(va, vb, vc);
    expand<<<65536, 256, 0, stream>>>(vc, vd, dmn, dmx, out);
}

// Round 8
// 305.993 us; speedup vs baseline: 1.0436x; 1.0436x over previous
//
#include <hip/hip_runtime.h>
#include <hip/hip_bf16.h>
#include <math.h>

typedef __attribute__((ext_vector_type(8))) short short8;
typedef __attribute__((ext_vector_type(4))) float f32x4;
typedef unsigned short u16;

#define Sn 1024
#define En 256
#define Hn 512
#define Ln 16

__device__ inline u16 bf16b(float x) {
    union { __hip_bfloat16 h; u16 u; } cvt;
    cvt.h = __float2bfloat16(x);
    return cvt.u;
}

// ---------------- K0: fused weight-pack + embed/GELU
__global__ void prep_embed(const float* __restrict__ wA, const float* __restrict__ wB,
                           const float* __restrict__ wS, u16* __restrict__ Wt,
                           const int* __restrict__ sent, const int* __restrict__ mask,
                           const float* __restrict__ ce_w, const float* __restrict__ me_w,
                           u16* __restrict__ vemb) {
    int bx = blockIdx.x;
    if (bx < 1088) {
        int idx = bx * 256 + threadIdx.x;
        int n = idx >> 8;
        int k = idx & 255;
        float v = 0.f;
        if (n < 512)       v = wA[k * 512 + n];
        else if (n < 1024) v = wB[k * 512 + (n - 512)];
        else if (n < 1040) v = wS[k * 16 + (n - 1024)];
        Wt[idx] = bf16b(v);
    } else {
        int row = bx - 1088;
        int e = threadIdx.x;
        int s = sent[row];
        int m = mask[row];
        float ce = ce_w[s * En + e];
        float me = me_w[m * En + e];
        float g = 0.5f * me * (1.f + erff(me * 0.70710678118654752f));
        vemb[row * En + e] = bf16b(ce * g);
    }
}

// ---------------- K1: GEMM1  C(4096 x 1040) = vemb(4096x256) @ W(256x1040)
// Epilogue by blockIdx.y: y<8 -> va(+bA) bf16; y in [8,16) -> sigmoid -> vb bf16;
// y==16 -> relu -> vd fp32 AND per-row min/max via shfl butterfly -> dmn/dmx.
#define LDP 136   // 128 + 8 pad (shorts)
__global__ __launch_bounds__(256, 2) void gemm1(const u16* __restrict__ A, const u16* __restrict__ Bt,
                                                const float* __restrict__ bA, const float* __restrict__ bB,
                                                const float* __restrict__ bS,
                                                u16* __restrict__ va, u16* __restrict__ vb,
                                                float* __restrict__ vd,
                                                float* __restrict__ dmn, float* __restrict__ dmx) {
    __shared__ __align__(16) u16 As[64 * LDP];
    __shared__ __align__(16) u16 Bs[64 * LDP];
    int tid = threadIdx.x;
    int m0 = blockIdx.x * 64, n0 = blockIdx.y * 64;
    int lane = tid & 63, w = tid >> 6;
    int lrow = lane & 15, quad = lane >> 4;

    f32x4 acc[4];
    for (int nt = 0; nt < 4; nt++) acc[nt] = (f32x4){0.f, 0.f, 0.f, 0.f};

    for (int kb = 0; kb < 2; kb++) {            // K = 256 = 2 * 128
        for (int i = 0; i < 4; i++) {
            int off = (i * 256 + tid) * 8;
            int r = off >> 7, c = off & 127;
            *(short8*)&As[r * LDP + c] = *(const short8*)&A[(m0 + r) * 256 + kb * 128 + c];
            *(short8*)&Bs[r * LDP + c] = *(const short8*)&Bt[(n0 + r) * 256 + kb * 128 + c];
        }
        __syncthreads();
        for (int ks = 0; ks < 4; ks++) {
            short8 a = *(const short8*)&As[(w * 16 + lrow) * LDP + ks * 32 + quad * 8];
            for (int nt = 0; nt < 4; nt++) {
                short8 b = *(const short8*)&Bs[(nt * 16 + lrow) * LDP + ks * 32 + quad * 8];
                acc[nt] = __builtin_amdgcn_mfma_f32_16x16x32_bf16(a, b, acc[nt], 0, 0, 0);
            }
        }
        __syncthreads();
    }
    int mbase = m0 + w * 16 + quad * 4;
    if (blockIdx.y < 8) {
        for (int nt = 0; nt < 4; nt++) {
            int n = n0 + nt * 16 + lrow;
            float bias = bA[n];
            for (int r = 0; r < 4; r++)
                va[(mbase + r) * 512 + n] = bf16b(acc[nt][r] + bias);
        }
    } else if (blockIdx.y < 16) {
        for (int nt = 0; nt < 4; nt++) {
            int n = n0 + nt * 16 + lrow - 512;
            float bias = bB[n];
            for (int r = 0; r < 4; r++) {
                float x = acc[nt][r] + bias;
                vb[(mbase + r) * 512 + n] = bf16b(1.f / (1.f + __expf(-x)));
            }
        }
    } else {
        float bias = bS[lrow];
        for (int r = 0; r < 4; r++) {
            float x = acc[0][r] + bias;
            x = x > 0.f ? x : 0.f;
            vd[(mbase + r) * 16 + lrow] = x;
            float mn = x, mx = x;
            for (int d = 1; d < 16; d <<= 1) {
                mn = fminf(mn, __shfl_xor(mn, d));
                mx = fmaxf(mx, __shfl_xor(mx, d));
            }
            if (lrow == 0) {
                dmn[mbase + r] = mn;
                dmx[mbase + r] = mx;
            }
        }
    }
}

// ---------------- K2: batched GEMM2  vc[b] = va[b](1024x512) @ vb[b]^T / H   (fp32 out)
__global__ __launch_bounds__(256, 2) void gemm2(const u16* __restrict__ va_g, const u16* __restrict__ vb_g,
                                                float* __restrict__ vc) {
    __shared__ __align__(16) u16 As[64 * LDP];
    __shared__ __align__(16) u16 Bs[64 * LDP];
    int tid = threadIdx.x;
    int b = blockIdx.z;
    int m0 = blockIdx.x * 64, n0 = blockIdx.y * 64;
    const u16* A  = va_g + (size_t)b * 1024 * 512;
    const u16* Bt = vb_g + (size_t)b * 1024 * 512;
    int lane = tid & 63, w = tid >> 6;
    int lrow = lane & 15, quad = lane >> 4;

    f32x4 acc[4];
    for (int nt = 0; nt < 4; nt++) acc[nt] = (f32x4){0.f, 0.f, 0.f, 0.f};

    for (int kb = 0; kb < 4; kb++) {            // K = 512 = 4 * 128
        for (int i = 0; i < 4; i++) {
            int off = (i * 256 + tid) * 8;
            int r = off >> 7, c = off & 127;
            *(short8*)&As[r * LDP + c] = *(const short8*)&A[(m0 + r) * 512 + kb * 128 + c];
            *(short8*)&Bs[r * LDP + c] = *(const short8*)&Bt[(n0 + r) * 512 + kb * 128 + c];
        }
        __syncthreads();
        for (int ks = 0; ks < 4; ks++) {
            short8 a = *(const short8*)&As[(w * 16 + lrow) * LDP + ks * 32 + quad * 8];
            for (int nt = 0; nt < 4; nt++) {
                short8 bfr = *(const short8*)&Bs[(nt * 16 + lrow) * LDP + ks * 32 + quad * 8];
                acc[nt] = __builtin_amdgcn_mfma_f32_16x16x32_bf16(a, bfr, acc[nt], 0, 0, 0);
            }
        }
        __syncthreads();
    }
    const float invH = 1.0f / 512.0f;
    float* C = vc + (size_t)b * 1024 * 1024;
    int mbase = m0 + w * 16 + quad * 4;
    for (int nt = 0; nt < 4; nt++) {
        int n = n0 + nt * 16 + lrow;
        for (int r = 0; r < 4; r++)
            C[(mbase + r) * 1024 + n] = acc[nt][r] * invH;
    }
}

// ---------------- K3: pred = softmax(vc[b,i,j] * vd[b,j,:]) over L=16; 4 lanes per group
__global__ __launch_bounds__(256) void expand(const float* __restrict__ vc, const float* __restrict__ vd,
                                              const float* __restrict__ dmn, const float* __restrict__ dmx,
                                              float* __restrict__ out) {
    int gid = blockIdx.x * 256 + threadIdx.x;   // 16,777,216 threads
    int t = gid & 3;
    int grp = gid >> 2;                          // (b*S+i)*S + j
    int j = grp & 1023;
    int bi = grp >> 10;
    int b = bi >> 10;
    float c = __builtin_nontemporal_load(&vc[grp]);
    int rowd = b * 1024 + j;
    f32x4 d = *(const f32x4*)&vd[rowd * 16 + t * 4];
    float m = (c >= 0.f) ? c * dmx[rowd] : c * dmn[rowd];
    float e0 = __expf(c * d.x - m);
    float e1 = __expf(c * d.y - m);
    float e2 = __expf(c * d.z - m);
    float e3 = __expf(c * d.w - m);
    float s = e0 + e1 + e2 + e3;
    s += __shfl_xor(s, 1);
    s += __shfl_xor(s, 2);
    float inv = 1.f / s;
    f32x4 o;
    o.x = e0 * inv; o.y = e1 * inv; o.z = e2 * inv; o.w = e3 * inv;
    __builtin_nontemporal_store(o, (f32x4*)&out[(size_t)grp * 16 + t * 4]);
}

extern "C" void kernel_launch(void* const* d_in, const int* in_sizes, int n_in,
                              void* d_out, int out_size, void* d_ws, size_t ws_size,
                              hipStream_t stream) {
    const int*   sent = (const int*)d_in[0];
    const int*   mask = (const int*)d_in[1];
    const float* ce_w = (const float*)d_in[2];
    const float* me_w = (const float*)d_in[3];
    const float* wA   = (const float*)d_in[4];
    const float* bA   = (const float*)d_in[5];
    const float* wB   = (const float*)d_in[6];
    const float* bB   = (const float*)d_in[7];
    const float* wS   = (const float*)d_in[8];
    const float* bS   = (const float*)d_in[9];
    float* out = (float*)d_out;

    char* ws = (char*)d_ws;
    u16* vemb = (u16*)ws;  ws += (size_t)4096 * 256 * 2;
    u16* Wt   = (u16*)ws;  ws += (size_t)1088 * 256 * 2;
    u16* va   = (u16*)ws;  ws += (size_t)4096 * 512 * 2;
    u16* vb   = (u16*)ws;  ws += (size_t)4096 * 512 * 2;
    float* vd  = (float*)ws;  ws += (size_t)4096 * 16 * 4;
    float* dmn = (float*)ws;  ws += (size_t)4096 * 4;
    float* dmx = (float*)ws;  ws += (size_t)4096 * 4;
    float* vc  = (float*)ws;  ws += (size_t)4 * 1024 * 1024 * 4;

    prep_embed<<<5184, 256, 0, stream>>>(wA, wB, wS, Wt, sent, mask, ce_w, me_w, vemb);
    gemm1<<<dim3(64, 17), 256, 0, stream>>>(vemb, Wt, bA, bB, bS, va, vb, vd, dmn, dmx);
    gemm2<<<dim3(16, 16, 4), 256, 0, stream>>>(va, vb, vc);
    expand<<<65536, 256, 0, stream>>>(vc, vd, dmn, dmx, out);
}